// Round 1
// 1212.712 us; speedup vs baseline: 1.3058x; 1.3058x over previous
//
#include <hip/hip_runtime.h>
#include <hip/hip_fp16.h>

// W8A16 GEMM: out[m,n] = (sum_k x[m,k]*w[n,k]) * scale[n] + bias[n]
// M=8192, K=4096, N=11008.
// Locked harness model (from absmax bit-pattern forensics r1-r3):
//   x: fp16 upcast to FLOAT32 [M,K]   (134 MB)
//   W: int8 widened to INT32  [N,K]   (180 MB)
//   scale, bias: float32 [N]
//   out: FLOAT32 [M,N]                (360 MB)
// Strategy: pre-convert x and W to fp16 in ws (both conversions EXACT), then a
// 256x256-tile 8-phase counted-vmcnt f16-MFMA GEMM (m201-lineage, T1+T2+T3/T4+T5),
// fp32 epilogue with scale+bias.

#define M_DIM 8192
#define K_DIM 4096
#define N_DIM 11008

// old (fallback) kernel tile params
#define TM 128
#define TN 128
#define BK 64
#define BKP 72

// new kernel grid params
#define MT_TILES 32              // 8192/256
#define NT_TILES 43              // 11008/256
#define NWG (MT_TILES * NT_TILES)  // 1376, % 8 == 0
#define CPX (NWG / 8)            // 172

typedef __attribute__((ext_vector_type(8))) _Float16 half8;  // 4 VGPRs
typedef __attribute__((ext_vector_type(4))) float floatx4;   // MFMA acc

union Pack16 { int4 i4; unsigned short u[8]; _Float16 h[8]; };

// ---------------- probe: widened int32 weights vs raw int8 bytes ----------------
__global__ __launch_bounds__(256) void probe_w(const int* __restrict__ W,
                                               unsigned int* __restrict__ f) {
    const size_t i0 = (size_t)blockIdx.x * 256 + threadIdx.x;
    const size_t stride = (size_t)gridDim.x * 256;
    int bad = 0;
    for (size_t i = i0; i < (size_t)(1u << 20); i += stride) {  // 4MB, in-bounds either way
        int w = W[i];
        if (w > 127 || w < -127) bad = 1;
    }
    if (bad) atomicOr(f, 1u);
}

// ---------------- x: fp32 -> fp16 (exact: values originate as fp16) ----------------
__global__ __launch_bounds__(256) void convert_x(const float* __restrict__ Xf,
                                                 unsigned short* __restrict__ Xh) {
    const size_t i = ((size_t)blockIdx.x * 256 + threadIdx.x) * 8;
    float4 a = *(const float4*)(Xf + i);
    float4 b = *(const float4*)(Xf + i + 4);
    Pack16 p;
    p.h[0] = (_Float16)a.x; p.h[1] = (_Float16)a.y;
    p.h[2] = (_Float16)a.z; p.h[3] = (_Float16)a.w;
    p.h[4] = (_Float16)b.x; p.h[5] = (_Float16)b.y;
    p.h[6] = (_Float16)b.z; p.h[7] = (_Float16)b.w;
    *(int4*)(Xh + i) = p.i4;
}

// ---------------- W: int32 (or raw int8 per flag) -> fp16 (exact, |v|<=127) ----------------
__global__ __launch_bounds__(256) void convert_w(const void* __restrict__ Wraw,
                                                 unsigned short* __restrict__ Wh,
                                                 const unsigned int* __restrict__ f) {
    const bool w8 = f[0] != 0u;
    const size_t i = ((size_t)blockIdx.x * 256 + threadIdx.x) * 8;  // weight index
    int v[8];
    if (w8) {
        int2 b = *(const int2*)((const char*)Wraw + i);
#pragma unroll
        for (int j = 0; j < 4; ++j)
            v[j] = (int)(signed char)(unsigned char)((((unsigned)b.x) >> (8 * j)) & 0xFFu);
#pragma unroll
        for (int j = 0; j < 4; ++j)
            v[4 + j] = (int)(signed char)(unsigned char)((((unsigned)b.y) >> (8 * j)) & 0xFFu);
    } else {
        const int4* src = (const int4*)((const int*)Wraw + i);
        int4 w0 = src[0], w1 = src[1];
        v[0] = w0.x; v[1] = w0.y; v[2] = w0.z; v[3] = w0.w;
        v[4] = w1.x; v[5] = w1.y; v[6] = w1.z; v[7] = w1.w;
    }
    Pack16 p;
#pragma unroll
    for (int j = 0; j < 8; ++j) p.h[j] = (_Float16)v[j];
    *(int4*)(Wh + i) = p.i4;
}

// ---------------- 8-phase 256x256 f16 MFMA GEMM ----------------
// LDS: lds[dbuf][op(A=0,B=1)][khalf] of 256 rows x 32 f16 (16 KB blocks) = 128 KiB.
// Swizzle (both-sides involution within a 16KB block, rule #21):
//   phys_byte = logical_byte ^ ((row & 6) << 3)   (row = byte>>6; flips byte bits 4,5)
// -> every 8-lane b128 service group hits 8 distinct 16B bank slots (conflict-free).
// Staging: global_load_lds dwordx4, LDS dest linear (wave base = wv*1024, +8192 for j=1),
// global source pre-swizzled per-lane.
// Schedule per iteration (2 K-tiles t0=2i buf0, t1=2i+1 buf1; u0=2i+2, u1=2i+3):
//   p1: rd buf0.kh0 B+A(mg0) | stage A.kh1(t1)->buf1 | bar lgkm mfma bar
//   p2: rd buf0.kh0 A(mg1)   | stage B.kh1(t1)->buf1
//   p3: rd buf0.kh1 B+A(mg0) | stage A.kh0(u0)->buf0
//   p4: rd buf0.kh1 A(mg1)   | stage B.kh0(u0)->buf0 | vmcnt(4)
//   p5: rd buf1.kh0 B+A(mg0) | stage A.kh1(u0)->buf0
//   p6: rd buf1.kh0 A(mg1)   | stage B.kh1(u0)->buf0
//   p7: rd buf1.kh1 B+A(mg0) | stage A.kh0(u1)->buf1
//   p8: rd buf1.kh1 A(mg1)   | stage B.kh0(u1)->buf1 | vmcnt(4)
// Proven: every read is confirmed by the preceding vmcnt(4)+barrier (stages <= W-2
// phases back have landed); every stage targets a region whose last ds_read was in an
// earlier phase (reads serviced before that phase's 2nd barrier; stage issued after it).
// Last iteration peeled with vmcnt(0) so skipped stages can't under-confirm.

__device__ __forceinline__ void gl16(const void* g, void* l) {
    __builtin_amdgcn_global_load_lds(
        (const __attribute__((address_space(1))) unsigned int*)g,
        (__attribute__((address_space(3))) unsigned int*)l, 16, 0, 0);
}

__global__ __launch_bounds__(512, 2) void w8a16_gemm_8ph(
    const unsigned short* __restrict__ Xh, const unsigned short* __restrict__ Wh,
    const float* __restrict__ scale, const float* __restrict__ bias,
    float* __restrict__ Out)
{
    __shared__ unsigned char lds[2][2][2][16384];  // [dbuf][A/B][khalf] 128 KiB

    const int t = threadIdx.x;       // 0..511
    const int lane = t & 63;
    const int wv = t >> 6;           // 0..7
    const int wr = wv >> 2;          // 0..1  (M)
    const int wc = wv & 3;           // 0..3  (N)
    const int fr = lane & 15;
    const int q  = lane >> 4;        // 0..3

    // T1: bijective XCD swizzle (1376 % 8 == 0), nt-fastest for A-panel L2 reuse
    const int bid = blockIdx.x;
    const int swz = (bid & 7) * CPX + (bid >> 3);
    const int mt = swz / NT_TILES;
    const int nt = swz - mt * NT_TILES;
    const size_t tileM = (size_t)mt << 8;
    const size_t tileN = (size_t)nt << 8;

    // --- stage source addressing (per thread, pre-swizzled global column) ---
    // phys p = j*8192 + t*16; row = p>>6; logical = p ^ ((row&6)<<3); col f16 = (logical&63)>>1
    const int rr = t >> 2;  // 0..127 (j adds 128)
    const int cA = ((((t & 3) << 4) ^ (((t >> 2) & 6) << 3)) >> 1);  // 0..31
    const unsigned short* srcA0 = Xh + (tileM + rr) * K_DIM + cA;
    const unsigned short* srcA1 = srcA0 + (size_t)128 * K_DIM;
    const unsigned short* srcB0 = Wh + (tileN + rr) * K_DIM + cA;
    const unsigned short* srcB1 = srcB0 + (size_t)128 * K_DIM;
    const int wvofs = wv << 10;  // wave-uniform LDS byte base within a 16KB block

    // --- ds_read fragment bases (byte offset in a 16KB block, swizzled) ---
    const int gsw = (fr & 6) << 3;
    const int rdA = ((((wr << 7) + fr) << 6) + (q << 4)) ^ gsw;
    const int rdB = ((((wc << 6) + fr) << 6) + (q << 4)) ^ gsw;

    floatx4 acc[8][4];
#pragma unroll
    for (int m = 0; m < 8; ++m)
#pragma unroll
        for (int n = 0; n < 4; ++n) acc[m][n] = (floatx4){0.f, 0.f, 0.f, 0.f};

    half8 afrag[4], bfrag[4];

#define STAGE_A(d_, kh_, tau_) do { \
    const unsigned short* _g0 = srcA0 + ((tau_) * 64 + (kh_) * 32); \
    const unsigned short* _g1 = srcA1 + ((tau_) * 64 + (kh_) * 32); \
    unsigned char* _l = &lds[d_][0][kh_][0] + wvofs; \
    gl16(_g0, _l); gl16(_g1, _l + 8192); \
} while (0)

#define STAGE_B(d_, kh_, tau_) do { \
    const unsigned short* _g0 = srcB0 + ((tau_) * 64 + (kh_) * 32); \
    const unsigned short* _g1 = srcB1 + ((tau_) * 64 + (kh_) * 32); \
    unsigned char* _l = &lds[d_][1][kh_][0] + wvofs; \
    gl16(_g0, _l); gl16(_g1, _l + 8192); \
} while (0)

#define VM4 asm volatile("s_waitcnt vmcnt(4)" ::: "memory")
#define VM0 asm volatile("s_waitcnt vmcnt(0)" ::: "memory")
#define NOSTG ((void)0)

#define PHASE(d_, kh_, mg_, RB_, STG_, VM_) do { \
    const unsigned char* _Ab = &lds[d_][0][kh_][0]; \
    const unsigned char* _Bb = &lds[d_][1][kh_][0]; \
    if (RB_) { \
        _Pragma("unroll") \
        for (int _n = 0; _n < 4; ++_n) \
            bfrag[_n] = *(const half8*)(const void*)(_Bb + rdB + _n * 1024); \
    } \
    _Pragma("unroll") \
    for (int _m = 0; _m < 4; ++_m) \
        afrag[_m] = *(const half8*)(const void*)(_Ab + rdA + (mg_) * 4096 + _m * 1024); \
    STG_; \
    VM_; \
    asm volatile("s_barrier" ::: "memory"); \
    asm volatile("s_waitcnt lgkmcnt(0)" ::: "memory"); \
    __builtin_amdgcn_sched_barrier(0); \
    __builtin_amdgcn_s_setprio(1); \
    _Pragma("unroll") \
    for (int _m = 0; _m < 4; ++_m) \
        _Pragma("unroll") \
        for (int _n = 0; _n < 4; ++_n) \
            acc[(mg_) * 4 + _m][_n] = __builtin_amdgcn_mfma_f32_16x16x32_f16( \
                afrag[_m], bfrag[_n], acc[(mg_) * 4 + _m][_n], 0, 0, 0); \
    __builtin_amdgcn_s_setprio(0); \
    asm volatile("s_barrier" ::: "memory"); \
} while (0)

    // prologue: stage K-tile 0 (all 4 halves) + K-tile 1 (kh0) = 12 loads/wave,
    // leave last 4 in flight.
    STAGE_A(0, 0, 0); STAGE_B(0, 0, 0); STAGE_A(0, 1, 0); STAGE_B(0, 1, 0);
    STAGE_A(1, 0, 1); STAGE_B(1, 0, 1);
    asm volatile("s_waitcnt vmcnt(4)" ::: "memory");
    asm volatile("s_barrier" ::: "memory");

#pragma unroll 1
    for (int i = 0; i < 31; ++i) {
        const int t1 = 2 * i + 1, u0 = 2 * i + 2, u1 = 2 * i + 3;
        PHASE(0, 0, 0, 1, STAGE_A(1, 1, t1), NOSTG);
        PHASE(0, 0, 1, 0, STAGE_B(1, 1, t1), NOSTG);
        PHASE(0, 1, 0, 1, STAGE_A(0, 0, u0), NOSTG);
        PHASE(0, 1, 1, 0, STAGE_B(0, 0, u0), VM4);
        PHASE(1, 0, 0, 1, STAGE_A(0, 1, u0), NOSTG);
        PHASE(1, 0, 1, 0, STAGE_B(0, 1, u0), NOSTG);
        PHASE(1, 1, 0, 1, STAGE_A(1, 0, u1), NOSTG);
        PHASE(1, 1, 1, 0, STAGE_B(1, 0, u1), VM4);
    }
    // peeled last iteration: t0=62 (buf0), t1=63 (buf1); only t1.kh1 still to stage.
    PHASE(0, 0, 0, 1, STAGE_A(1, 1, 63), NOSTG);
    PHASE(0, 0, 1, 0, STAGE_B(1, 1, 63), NOSTG);
    PHASE(0, 1, 0, 1, NOSTG, NOSTG);
    PHASE(0, 1, 1, 0, NOSTG, VM0);
    PHASE(1, 0, 0, 1, NOSTG, NOSTG);
    PHASE(1, 0, 1, 0, NOSTG, NOSTG);
    PHASE(1, 1, 0, 1, NOSTG, NOSTG);
    PHASE(1, 1, 1, 0, NOSTG, NOSTG);

#undef PHASE
#undef STAGE_A
#undef STAGE_B
#undef VM4
#undef VM0
#undef NOSTG

    // epilogue: C/D layout col=lane&15, row=(lane>>4)*4+reg (m89/m91-verified)
    const int rbase = q << 2;
#pragma unroll
    for (int ni = 0; ni < 4; ++ni) {
        const int n = (int)tileN + (wc << 6) + (ni << 4) + fr;
        const float s = scale[n];
        const float bz = bias[n];
#pragma unroll
        for (int mi = 0; mi < 8; ++mi) {
            const size_t m = tileM + (size_t)((wr << 7) + (mi << 4) + rbase);
#pragma unroll
            for (int r = 0; r < 4; ++r)
                Out[(m + r) * N_DIM + n] = acc[mi][ni][r] * s + bz;
        }
    }
}

// ---------------- fallback GEMM (old 128x128, inline/partial convert) ----------------
template <bool XPRE, bool WPRE>
__global__ __launch_bounds__(256) void w8a16_gemm(
    const float* __restrict__ Xf, const unsigned short* __restrict__ Xh,
    const int* __restrict__ Wi, const unsigned short* __restrict__ Wh,
    const float* __restrict__ scale, const float* __restrict__ bias,
    float* __restrict__ Out)
{
    __shared__ unsigned short As[TM * BKP];
    __shared__ unsigned short Bs[TN * BKP];

    const int t = threadIdx.x;
    const int lane = t & 63;
    const int wave = t >> 6;
    const int tileM = blockIdx.y * TM;
    const int tileN = blockIdx.x * TN;
    const int wm = (wave & 1) * 64;
    const int wn = (wave >> 1) * 64;
    const int fr = lane & 15;
    const int fk = (lane >> 4) * 8;

    floatx4 acc[4][4];
#pragma unroll
    for (int mi = 0; mi < 4; ++mi)
#pragma unroll
        for (int ni = 0; ni < 4; ++ni) acc[mi][ni] = (floatx4){0.f, 0.f, 0.f, 0.f};

    for (int k0 = 0; k0 < K_DIM; k0 += BK) {
#pragma unroll
        for (int it = 0; it < 4; ++it) {
            const int c = it * 256 + t;
            const int r = c >> 3;
            const int qq = c & 7;
            if (XPRE) {
                *(int4*)(As + r * BKP + qq * 8) =
                    *(const int4*)(Xh + (size_t)(tileM + r) * K_DIM + k0 + qq * 8);
            } else {
                const float* s = Xf + (size_t)(tileM + r) * K_DIM + k0 + qq * 8;
                float4 x0 = ((const float4*)s)[0];
                float4 x1 = ((const float4*)s)[1];
                Pack16 p;
                p.h[0] = (_Float16)x0.x; p.h[1] = (_Float16)x0.y;
                p.h[2] = (_Float16)x0.z; p.h[3] = (_Float16)x0.w;
                p.h[4] = (_Float16)x1.x; p.h[5] = (_Float16)x1.y;
                p.h[6] = (_Float16)x1.z; p.h[7] = (_Float16)x1.w;
                *(int4*)(As + r * BKP + qq * 8) = p.i4;
            }
            if (WPRE) {
                *(int4*)(Bs + r * BKP + qq * 8) =
                    *(const int4*)(Wh + (size_t)(tileN + r) * K_DIM + k0 + qq * 8);
            } else {
                const int* s = Wi + (size_t)(tileN + r) * K_DIM + k0 + qq * 8;
                int4 w0 = ((const int4*)s)[0];
                int4 w1 = ((const int4*)s)[1];
                Pack16 p;
                p.h[0] = (_Float16)w0.x; p.h[1] = (_Float16)w0.y;
                p.h[2] = (_Float16)w0.z; p.h[3] = (_Float16)w0.w;
                p.h[4] = (_Float16)w1.x; p.h[5] = (_Float16)w1.y;
                p.h[6] = (_Float16)w1.z; p.h[7] = (_Float16)w1.w;
                *(int4*)(Bs + r * BKP + qq * 8) = p.i4;
            }
        }
        __syncthreads();
#pragma unroll
        for (int kh = 0; kh < 2; ++kh) {
            half8 a[4], b[4];
#pragma unroll
            for (int i = 0; i < 4; ++i)
                a[i] = *(const half8*)(const void*)(As + (wm + i * 16 + fr) * BKP + kh * 32 + fk);
#pragma unroll
            for (int i = 0; i < 4; ++i)
                b[i] = *(const half8*)(const void*)(Bs + (wn + i * 16 + fr) * BKP + kh * 32 + fk);
#pragma unroll
            for (int mi = 0; mi < 4; ++mi)
#pragma unroll
                for (int ni = 0; ni < 4; ++ni)
                    acc[mi][ni] = __builtin_amdgcn_mfma_f32_16x16x32_f16(
                        a[mi], b[ni], acc[mi][ni], 0, 0, 0);
        }
        __syncthreads();
    }

    const int rbase = (lane >> 4) * 4;
#pragma unroll
    for (int ni = 0; ni < 4; ++ni) {
        const int n = tileN + wn + ni * 16 + fr;
        const float s = scale[n];
        const float bz = bias[n];
#pragma unroll
        for (int mi = 0; mi < 4; ++mi) {
            const int m = tileM + wm + mi * 16 + rbase;
#pragma unroll
            for (int r = 0; r < 4; ++r)
                Out[(size_t)(m + r) * N_DIM + n] = acc[mi][ni][r] * s + bz;
        }
    }
}

extern "C" void kernel_launch(void* const* d_in, const int* in_sizes, int n_in,
                              void* d_out, int out_size, void* d_ws, size_t ws_size,
                              hipStream_t stream) {
    // --- resolve inputs BY SIZE (robust to pytree vs insertion ordering) ---
    const long long SZ_X = (long long)M_DIM * K_DIM;  // 33,554,432
    const long long SZ_W = (long long)N_DIM * K_DIM;  // 45,088,768
    const void *pX = nullptr, *pW = nullptr, *pS = nullptr, *pB = nullptr;
    int smallIdx[8];
    int nSmall = 0;
    for (int i = 0; i < n_in; ++i) {
        long long s = in_sizes[i];
        if (s == SZ_X && !pX) pX = d_in[i];
        else if (s == SZ_W && !pW) pW = d_in[i];
        else if (s == (long long)N_DIM && nSmall < 8) smallIdx[nSmall++] = i;
    }
    if (nSmall == 2) {
        if (smallIdx[0] == 2)      { pS = d_in[2]; pB = d_in[smallIdx[1]]; }
        else if (smallIdx[1] == 2) { pS = d_in[2]; pB = d_in[smallIdx[0]]; }
        else                       { pS = d_in[smallIdx[0]]; pB = d_in[smallIdx[1]]; }
    }
    if (!pX || !pW || !pS || !pB) { pX = d_in[0]; pW = d_in[1]; pS = d_in[2]; pB = d_in[3]; }

    const float* Xf = (const float*)pX;
    const int* Wi = (const int*)pW;
    const float* scale = (const float*)pS;
    const float* bias = (const float*)pB;
    float* Out = (float*)d_out;

    dim3 gridOld(N_DIM / TN, M_DIM / TM);  // 86 x 64
    const size_t OFF = 256;
    const size_t XH_BYTES = (size_t)SZ_X * 2;  // 67 MB fp16 x
    const size_t WH_BYTES = (size_t)SZ_W * 2;  // 90 MB fp16 w

    if (ws_size >= OFF + XH_BYTES + WH_BYTES + 64) {
        unsigned int* flags = (unsigned int*)d_ws;
        unsigned short* Xh = (unsigned short*)((char*)d_ws + OFF);
        unsigned short* Wh = (unsigned short*)((char*)d_ws + OFF + XH_BYTES);
        hipMemsetAsync(flags, 0, 4, stream);
        probe_w<<<256, 256, 0, stream>>>(Wi, flags);
        convert_x<<<(int)(SZ_X / 8 / 256), 256, 0, stream>>>(Xf, Xh);
        convert_w<<<(int)(SZ_W / 8 / 256), 256, 0, stream>>>(pW, Wh, flags);
        w8a16_gemm_8ph<<<dim3(NWG), dim3(512), 0, stream>>>(Xh, Wh, scale, bias, Out);
    } else if (ws_size >= OFF + WH_BYTES + 64) {
        unsigned int* flags = (unsigned int*)d_ws;
        unsigned short* Wh = (unsigned short*)((char*)d_ws + OFF);
        hipMemsetAsync(flags, 0, 4, stream);
        probe_w<<<256, 256, 0, stream>>>(Wi, flags);
        convert_w<<<(int)(SZ_W / 8 / 256), 256, 0, stream>>>(pW, Wh, flags);
        w8a16_gemm<false, true><<<gridOld, 256, 0, stream>>>(Xf, nullptr, Wi, Wh, scale, bias, Out);
    } else {
        w8a16_gemm<false, false><<<gridOld, 256, 0, stream>>>(Xf, nullptr, Wi, nullptr, scale, bias, Out);
    }
}